// Round 11
// baseline (6425.843 us; speedup 1.0000x reference)
//
#include <hip/hip_runtime.h>
#include <math.h>
#include <stdint.h>

#define BB     64
#define TENC   100
#define TDEC   50
#define LDIM   512
#define EE     512
#define HDIM   512
#define FIVEL  2560
#define RSTEPS 8
#define VOUT   30000
#define NB2    470     // 64-col partial chunks per logit row (470*64 = 30080)

typedef __attribute__((ext_vector_type(8))) short short8v;   // 8 x bf16
typedef __attribute__((ext_vector_type(4))) float floatx4;
typedef unsigned short ushort_t;

#define AS1 __attribute__((address_space(1)))
#define AS3 __attribute__((address_space(3)))

// ---------------- workspace offsets (float units) ----------------
static const size_t OFF_A        = 0;
static const size_t OFF_WIT_ENC  = 8192000;
static const size_t OFF_ENCX     = 8847360;    // ends 10,485,760
static const size_t OFF_LOGWT    = 0;
static const size_t OFF_DECH     = 7680000;    // ends 8,499,200
static const size_t OFF_DECPRE   = 8499200;    // ends 12,595,200
static const size_t OFF_ENC_HS   = 13107200;   // 1,638,400
static const size_t OFF_TPW      = 13107200;   // aliases enc_hs slots 0..40 post-review
static const size_t OFF_ENC_WHT  = 14745600;   // 655,360
static const size_t OFF_REVWC    = 15400960;   // 10,485,760 (dead post-review)
static const size_t OFF_PART     = 15400960;   // logit partials (aliases REVWC)
static const size_t OFF_DECWC    = 25886720;   // decWhT 655,360 + WaT_dec 655,360
static const size_t OFF_WIT_DEC  = 27197440;   // 655,360
static const size_t OFF_REVWT    = 27852800;   // 1,048,576
static const size_t OFF_DECWT    = 28901376;   // 131,072
static const size_t OFF_REVWH2AT = 29032448;   // 1,048,576
static const size_t OFF_DECWH2AT = 30081024;   // 131,072
static const size_t OFF_DECX     = 30212096;   // 819,200
static const size_t OFF_THOUGHT  = 31031296;   // 131,072
static const size_t OFF_TPROJ    = 31162368;   // 131,072
static const size_t OFF_HB0      = 31293440;   // 16,384
static const size_t OFF_HB1      = 31309824;   // 16,384
static const size_t OFF_ATTV     = 31326208;   // 16,384
static const size_t OFF_H0       = 31342592;   // 16,384 (unused)
static const size_t OFF_C0       = 31358976;   // 4 x 32,768
static const size_t OFF_SBUF     = 31490048;   // 163,840 (64 x 2560 fp32)  [buf 0]
static const size_t OFF_SBUF1    = 31653888;   // 163,840                    [buf 1]
static const size_t OFF_ALPHA    = 31817728;   // 512
static const size_t WS_TOTAL     = 31818240;   // 127.27 MB (< 127.93 proven in R1)

__device__ __forceinline__ float sigmoidf_(float x) { return 1.0f / (1.0f + __expf(-x)); }
__device__ __forceinline__ float tanh_fast(float x) { return 1.0f - 2.0f / (__expf(2.0f * x) + 1.0f); }
__device__ __forceinline__ unsigned short f2bf(float x) {
    unsigned u = __float_as_uint(x);
    u += 0x7FFFu + ((u >> 16) & 1u);
    return (unsigned short)(u >> 16);
}
__device__ __forceinline__ float bf2f(unsigned short h) {
    return __uint_as_float(((unsigned)h) << 16);
}

// ---------------------------------------------------------------------------
__global__ __launch_bounds__(128)
void gather_embed(const float* __restrict__ embed, const int* __restrict__ tok,
                  int T, ushort_t* __restrict__ X)
{
    int m = blockIdx.x, t = m / BB, b = m % BB;
    const float* src = embed + (size_t)tok[b * T + t] * EE;
    float4 v = *(const float4*)(src + threadIdx.x * 4);
    ushort4 o = { f2bf(v.x), f2bf(v.y), f2bf(v.z), f2bf(v.w) };
    *(ushort4*)(X + (size_t)m * EE + threadIdx.x * 4) = o;
}

// ---------------------------------------------------------------------------
// Transpose bodies. Generic (logit), 5-way batched (512->2560), rev-comb
// (z=16: Wh/Wa with kofs), square-pair (z-split).
// ---------------------------------------------------------------------------
__device__ __forceinline__ void transpose_body(const float* __restrict__ W,
                                               ushort_t* __restrict__ WT,
                                               int N, int ldWT, int kofs)
{
    __shared__ float tile[32][33];
    int n0 = blockIdx.x * 32, k0 = blockIdx.y * 32;
    int tx = threadIdx.x & 31, ty = threadIdx.x >> 5;
    #pragma unroll
    for (int i = 0; i < 4; ++i) {
        int k = k0 + ty + i * 8, n = n0 + tx;
        tile[ty + i * 8][tx] = (n < N) ? W[(size_t)k * N + n] : 0.f;
    }
    __syncthreads();
    #pragma unroll
    for (int i = 0; i < 4; ++i) {
        int n = n0 + ty + i * 8, k = k0 + tx;
        if (n < N) WT[(size_t)n * ldWT + kofs + k] = f2bf(tile[tx][ty + i * 8]);
    }
}

__global__ __launch_bounds__(256)
void conv_transpose(const float* __restrict__ W, ushort_t* __restrict__ WT,
                    int N, int ldWT, int kofs)
{
    transpose_body(W, WT, N, ldWT, kofs);
}

__global__ __launch_bounds__(256)
void conv_transpose5(const float* W0, const float* W1, const float* W2,
                     const float* W3, const float* W4,
                     ushort_t* D0, ushort_t* D1, ushort_t* D2,
                     ushort_t* D3, ushort_t* D4)
{
    const float* W; ushort_t* D;
    switch (blockIdx.z) {
        case 0:  W = W0; D = D0; break;
        case 1:  W = W1; D = D1; break;
        case 2:  W = W2; D = D2; break;
        case 3:  W = W3; D = D3; break;
        default: W = W4; D = D4; break;
    }
    transpose_body(W, D, FIVEL, 512, 0);
}

__global__ __launch_bounds__(256)
void conv_transpose_rev(const float* __restrict__ Wh, const float* __restrict__ Wa,
                        ushort_t* __restrict__ WT)
{
    int zz = blockIdx.z;          // 0..15
    int r = zz & 7;
    const float* W = (zz < 8 ? Wh : Wa) + (size_t)r * 1310720;
    ushort_t* D = WT + (size_t)r * 2621440;
    transpose_body(W, D, FIVEL, 1024, (zz < 8) ? 0 : 512);
}

__global__ __launch_bounds__(256)
void conv_transpose_sq(const float* __restrict__ A0, const float* __restrict__ A1,
                       ushort_t* __restrict__ D0, ushort_t* __restrict__ D1,
                       int zsplit, long Wz, long WTz)
{
    int zz = blockIdx.z;
    const float* W; ushort_t* D;
    if (zz < zsplit) { W = A0 + (size_t)zz * Wz; D = D0 + (size_t)zz * WTz; }
    else             { W = A1 + (size_t)(zz - zsplit) * Wz; D = D1 + (size_t)(zz - zsplit) * WTz; }
    transpose_body(W, D, 512, 512, 0);
}

// ---------------------------------------------------------------------------
// bf16 MFMA GEMM, bf16 out, LDS-staged coalesced epilogue (R8-proven).
// ---------------------------------------------------------------------------
__global__ __launch_bounds__(256)
void gemm_bf16(const ushort_t* __restrict__ A, const ushort_t* __restrict__ BT,
               const float* __restrict__ bias, ushort_t* __restrict__ Cb,
               int N, int K, long ldc)
{
    __shared__ ushort_t lds[2][128][32];
    __shared__ ushort_t ctile[128 * 128];
    const int tid  = threadIdx.x;
    const int wave = tid >> 6, lane = tid & 63;
    const int m0 = blockIdx.y * 128, n0 = blockIdx.x * 128;
    const int wr = wave >> 1, wc = wave & 1;

    floatx4 acc[4][4] = {};
    const int sr  = lane >> 2;
    const int scp = lane & 3;

    for (int k0 = 0; k0 < K; k0 += 32) {
        #pragma unroll
        for (int half = 0; half < 2; ++half) {
            int rbase = wave * 32 + half * 16;
            int r = rbase + sr;
            int c = scp ^ ((r >> 1) & 3);
            const ushort_t* ga = A + (size_t)(m0 + r) * K + k0 + c * 8;
            const ushort_t* gb = BT + (size_t)(n0 + r) * K + k0 + c * 8;
            __builtin_amdgcn_global_load_lds(
                (const AS1 void*)ga, (AS3 void*)&lds[0][rbase][0], 16, 0, 0);
            __builtin_amdgcn_global_load_lds(
                (const AS1 void*)gb, (AS3 void*)&lds[1][rbase][0], 16, 0, 0);
        }
        __syncthreads();

        short8v af[4], bv[4];
        #pragma unroll
        for (int i = 0; i < 4; ++i) {
            int ra = wr * 64 + i * 16 + (lane & 15);
            int ca = (lane >> 4) ^ ((ra >> 1) & 3);
            af[i] = *(const short8v*)&lds[0][ra][ca * 8];
            int rb = wc * 64 + i * 16 + (lane & 15);
            int cb = (lane >> 4) ^ ((rb >> 1) & 3);
            bv[i] = *(const short8v*)&lds[1][rb][cb * 8];
        }
        #pragma unroll
        for (int i = 0; i < 4; ++i)
            #pragma unroll
            for (int j = 0; j < 4; ++j)
                acc[i][j] = __builtin_amdgcn_mfma_f32_16x16x32_bf16(af[i], bv[j], acc[i][j], 0, 0, 0);
        __syncthreads();
    }

    const int crow0 = wr * 64 + (lane >> 4) * 4;
    const int ccol0 = wc * 64 + (lane & 15);
    #pragma unroll
    for (int i = 0; i < 4; ++i) {
        #pragma unroll
        for (int j = 0; j < 4; ++j) {
            int col = ccol0 + j * 16;
            float bval = bias ? bias[n0 + col] : 0.f;
            #pragma unroll
            for (int rr = 0; rr < 4; ++rr)
                ctile[(crow0 + i * 16 + rr) * 128 + col] = f2bf(acc[i][j][rr] + bval);
        }
    }
    __syncthreads();
    #pragma unroll
    for (int itc = 0; itc < 8; ++itc) {
        int chunk = itc * 256 + tid;
        int row = chunk >> 4, ch = chunk & 15;
        *(short8v*)(Cb + (size_t)(m0 + row) * ldc + n0 + ch * 8) =
            *(const short8v*)&ctile[row * 128 + ch * 8];
    }
}

// ---------------------------------------------------------------------------
// Logit GEMM (R10): XCD-chunked M-fast swizzle, fused softmax partials,
// LDS-staged fp32 epilogue, row remap, full-cacheline stores.
// ---------------------------------------------------------------------------
__global__ __launch_bounds__(256)
void gemm_logit(const ushort_t* __restrict__ A, const ushort_t* __restrict__ BT,
                const float* __restrict__ bias, float* __restrict__ C,
                float2* __restrict__ part, int N, int K)
{
    __shared__ ushort_t lds[2][128][32];
    __shared__ float ctf[128 * 128];
    const int tid  = threadIdx.x;
    const int wave = tid >> 6, lane = tid & 63;
    int lin = blockIdx.x;
    int xcd = lin & 7, o = lin >> 3;
    int wgid = (xcd < 3 ? xcd * 735 + o : 3 * 735 + (xcd - 3) * 734 + o);
    const int ntile = wgid / 25, mtile = wgid % 25;
    const int m0 = mtile * 128, n0 = ntile * 128;
    const int wr = wave >> 1, wc = wave & 1;

    floatx4 acc[4][4] = {};
    const int sr  = lane >> 2;
    const int scp = lane & 3;

    for (int k0 = 0; k0 < K; k0 += 32) {
        #pragma unroll
        for (int half = 0; half < 2; ++half) {
            int rbase = wave * 32 + half * 16;
            int r = rbase + sr;
            int c = scp ^ ((r >> 1) & 3);
            const ushort_t* ga = A + (size_t)(m0 + r) * K + k0 + c * 8;
            int nr = n0 + r; if (nr >= N) nr = 0;
            const ushort_t* gb = BT + (size_t)nr * K + k0 + c * 8;
            __builtin_amdgcn_global_load_lds(
                (const AS1 void*)ga, (AS3 void*)&lds[0][rbase][0], 16, 0, 0);
            __builtin_amdgcn_global_load_lds(
                (const AS1 void*)gb, (AS3 void*)&lds[1][rbase][0], 16, 0, 0);
        }
        __syncthreads();

        short8v af[4], bv[4];
        #pragma unroll
        for (int i = 0; i < 4; ++i) {
            int ra = wr * 64 + i * 16 + (lane & 15);
            int ca = (lane >> 4) ^ ((ra >> 1) & 3);
            af[i] = *(const short8v*)&lds[0][ra][ca * 8];
            int rb = wc * 64 + i * 16 + (lane & 15);
            int cb = (lane >> 4) ^ ((rb >> 1) & 3);
            bv[i] = *(const short8v*)&lds[1][rb][cb * 8];
        }
        #pragma unroll
        for (int i = 0; i < 4; ++i)
            #pragma unroll
            for (int j = 0; j < 4; ++j)
                acc[i][j] = __builtin_amdgcn_mfma_f32_16x16x32_bf16(af[i], bv[j], acc[i][j], 0, 0, 0);
        __syncthreads();
    }

    const int cn = lane & 15, qq = lane >> 4;
    const int lcol0 = wc * 64 + cn;
    float bv[4]; bool valid[4];
    #pragma unroll
    for (int j = 0; j < 4; ++j) {
        int col = n0 + lcol0 + j * 16;
        valid[j] = col < N;
        bv[j] = valid[j] ? bias[col] : 0.f;
    }
    const int nb2 = ntile * 2 + wc;
    #pragma unroll
    for (int i = 0; i < 4; ++i) {
        #pragma unroll
        for (int rr = 0; rr < 4; ++rr) {
            int lrow = wr * 64 + qq * 4 + i * 16 + rr;
            int m = m0 + lrow;
            float v[4];
            #pragma unroll
            for (int j = 0; j < 4; ++j)
                v[j] = valid[j] ? acc[i][j][rr] + bv[j] : -3.0e38f;
            float mx = fmaxf(fmaxf(v[0], v[1]), fmaxf(v[2], v[3]));
            #pragma unroll
            for (int msk = 1; msk < 16; msk <<= 1) mx = fmaxf(mx, __shfl_xor(mx, msk));
            float sm = 0.f;
            #pragma unroll
            for (int j = 0; j < 4; ++j) if (valid[j]) sm += __expf(v[j] - mx);
            #pragma unroll
            for (int msk = 1; msk < 16; msk <<= 1) sm += __shfl_xor(sm, msk);
            if (cn == 0) part[(size_t)m * NB2 + nb2] = make_float2(mx, sm);
            #pragma unroll
            for (int j = 0; j < 4; ++j)
                ctf[lrow * 128 + lcol0 + j * 16] = v[j];
        }
    }
    __syncthreads();
    #pragma unroll
    for (int itc = 0; itc < 16; ++itc) {
        int chunk = itc * 256 + tid;
        int row = chunk >> 5, ch = chunk & 31;
        int col = n0 + ch * 4;
        if (col < N) {
            int m = m0 + row;
            int t = m >> 6, bb = m & 63;
            float* dst = C + ((size_t)bb * TDEC + t) * VOUT + col;
            if (col + 3 < N) {
                *(floatx4*)dst = *(const floatx4*)&ctf[row * 128 + ch * 4];
            } else {
                for (int e = 0; e < 4 && col + e < N; ++e)
                    dst[e] = ctf[row * 128 + ch * 4 + e];
            }
        }
    }
}

// ---------------------------------------------------------------------------
__global__ __launch_bounds__(256)
void logsm_sub(float* __restrict__ out, const float2* __restrict__ part)
{
    const int r = blockIdx.x;
    const int b = r / TDEC, t = r % TDEC;
    const int m = t * 64 + b;
    const int tid = threadIdx.x, wave = tid >> 6, lane = tid & 63;
    float M = -3.0e38f, S = 0.f;
    for (int i = tid; i < NB2; i += 256) {
        float2 p = part[(size_t)m * NB2 + i];
        float nm = fmaxf(M, p.x);
        S = S * __expf(M - nm) + p.y * __expf(p.x - nm);
        M = nm;
    }
    #pragma unroll
    for (int off = 32; off; off >>= 1) {
        float Mo = __shfl_xor(M, off), So = __shfl_xor(S, off);
        float nm = fmaxf(M, Mo);
        S = S * __expf(M - nm) + So * __expf(Mo - nm);
        M = nm;
    }
    __shared__ float ms[4], ss[4];
    if (lane == 0) { ms[wave] = M; ss[wave] = S; }
    __syncthreads();
    float M2 = fmaxf(fmaxf(ms[0], ms[1]), fmaxf(ms[2], ms[3]));
    float S2 = ss[0] * __expf(ms[0] - M2) + ss[1] * __expf(ms[1] - M2) +
               ss[2] * __expf(ms[2] - M2) + ss[3] * __expf(ms[3] - M2);
    float lse = M2 + __logf(S2);
    floatx4* row = (floatx4*)(out + (size_t)r * VOUT);
    for (int i = tid; i < VOUT / 4; i += 256) {
        floatx4 x = __builtin_nontemporal_load(row + i);
        x[0] -= lse; x[1] -= lse; x[2] -= lse; x[3] -= lse;
        __builtin_nontemporal_store(x, row + i);
    }
}

// ---------------------------------------------------------------------------
// Merged encoder step (one launch per t). 80 blocks x 256 thr.
// Prologue (all blocks, redundant): h(t-1),c(t-1) = LSTM-epi(sprev, pre, bh,
// c_in); h -> LDS. Blocks 0-7 write c(t-1) and h(t-1)->h_store (rows k*8..).
// Main: sout[64][2560] cols [n0,n0+32) = h(t-1) @ WhT (B LDS-staged).
// sprev == null means s(t-1) GEMM part is zero (t==1).
// ---------------------------------------------------------------------------
__global__ __launch_bounds__(256)
void enc_step_fused(const float* __restrict__ sprev,
                    const ushort_t* __restrict__ pre,
                    const float* __restrict__ bh,
                    const float* __restrict__ c_in, float* __restrict__ c_out,
                    ushort_t* __restrict__ h_store,
                    const ushort_t* __restrict__ WhT,
                    float* __restrict__ sout)
{
    __shared__ ushort_t hl[64][520];    // 66.56 KB (pad -> 2-way banks only)
    __shared__ ushort_t Bl[32][520];    // 33.28 KB
    const int tid = threadIdx.x, wave = tid >> 6, lane = tid & 63;
    const int n0 = blockIdx.x * 32;

    // stage B early (independent of epilogue) — one 1KB row per wave-instr
    for (int r = wave; r < 32; r += 4) {
        const ushort_t* src = WhT + (size_t)(n0 + r) * 512 + lane * 8;
        __builtin_amdgcn_global_load_lds(
            (const AS1 void*)src, (AS3 void*)&Bl[r][0], 16, 0, 0);
    }

    // epilogue: thread owns cols [col4, col4+4), rows [r0, r0+32)
    const int col4 = (tid & 127) * 4;
    const int r0 = (tid >> 7) * 32;
    float b0[5][4];
    #pragma unroll
    for (int g = 0; g < 5; ++g)
        *(floatx4*)b0[g] = *(const floatx4*)(bh + g * 512 + col4);
    const bool writerBlk = blockIdx.x < 8;
    const int wrow0 = blockIdx.x * 8;          // rows this block persists

    #pragma unroll 4
    for (int rr = 0; rr < 32; ++rr) {
        int row = r0 + rr;
        float sg[5][4];
        #pragma unroll
        for (int g = 0; g < 5; ++g) {
            floatx4 sv;
            if (sprev) sv = *(const floatx4*)(sprev + (size_t)row * FIVEL + g * 512 + col4);
            else       sv = (floatx4){0.f, 0.f, 0.f, 0.f};
            ushort4 p = *(const ushort4*)(pre + (size_t)row * FIVEL + g * 512 + col4);
            sg[g][0] = sv[0] + bf2f(p.x) + b0[g][0];
            sg[g][1] = sv[1] + bf2f(p.y) + b0[g][1];
            sg[g][2] = sv[2] + bf2f(p.z) + b0[g][2];
            sg[g][3] = sv[3] + bf2f(p.w) + b0[g][3];
        }
        floatx4 ci = *(const floatx4*)(c_in + (size_t)row * 512 + col4);
        floatx4 co;
        ushort4 ho;
        unsigned short hv[4];
        #pragma unroll
        for (int e = 0; e < 4; ++e) {
            float ig = sigmoidf_(sg[0][e]), fg = sigmoidf_(sg[1][e]), og = sigmoidf_(sg[2][e]);
            float tt = fmaxf(sg[3][e], sg[4][e]);
            float c2 = fg * ci[e] + ig * tt;
            co[e] = c2;
            hv[e] = f2bf(og * tanh_fast(c2));
        }
        ho = make_ushort4(hv[0], hv[1], hv[2], hv[3]);
        *(ushort4*)&hl[row][col4] = ho;
        if (writerBlk && row >= wrow0 && row < wrow0 + 8) {
            *(floatx4*)(c_out + (size_t)row * 512 + col4) = co;
            *(ushort4*)(h_store + (size_t)row * 512 + col4) = ho;
        }
    }
    __syncthreads();

    // MFMA: wave w -> A-rows [w*16, w*16+16), 2 col-tiles of 16
    const int q = lane >> 4, cn = lane & 15;
    const int arow = wave * 16 + cn;
    floatx4 acc[2] = {};
    #pragma unroll
    for (int kt = 0; kt < 16; ++kt) {
        short8v af = *(const short8v*)&hl[arow][kt * 32 + q * 8];
        #pragma unroll
        for (int tl = 0; tl < 2; ++tl) {
            short8v bf = *(const short8v*)&Bl[tl * 16 + cn][kt * 32 + q * 8];
            acc[tl] = __builtin_amdgcn_mfma_f32_16x16x32_bf16(af, bf, acc[tl], 0, 0, 0);
        }
    }
    #pragma unroll
    for (int tl = 0; tl < 2; ++tl)
        #pragma unroll
        for (int rr = 0; rr < 4; ++rr)
            sout[(size_t)(wave * 16 + q * 4 + rr) * FIVEL + n0 + tl * 16 + cn] = acc[tl][rr];
}

// ---------------------------------------------------------------------------
// Step GEMM phase A (R8-proven): s[64][2560] = [a0|a1] @ BT^T. 160 blocks.
// ---------------------------------------------------------------------------
template<int NSEG>
__global__ __launch_bounds__(256)
void step_gemm(const ushort_t* __restrict__ a0, const ushort_t* __restrict__ a1,
               const ushort_t* __restrict__ BT, int ldBT, float* __restrict__ sbuf)
{
    constexpr int K = NSEG * 512;
    constexpr int LROW = K + 8;
    __shared__ ushort_t Bl[16 * LROW];
    const int tid = threadIdx.x, wave = tid >> 6, lane = tid & 63;
    const int q = lane >> 4, cn = lane & 15;
    const int n0 = blockIdx.x * 16;

    #pragma unroll
    for (int it = 0; it < NSEG * 4; ++it) {
        int slot = it * 4 + wave;
        int row  = slot / NSEG;
        int part = slot % NSEG;
        const ushort_t* src = BT + (size_t)(n0 + row) * ldBT + part * 512 + lane * 8;
        __builtin_amdgcn_global_load_lds(
            (const AS1 void*)src, (AS3 void*)&Bl[row * LROW + part * 512], 16, 0, 0);
    }
    __syncthreads();

    floatx4 acc = {0.f, 0.f, 0.f, 0.f};
    {
        const ushort_t* Ap = a0 + (size_t)(wave * 16 + cn) * 512 + q * 8;
        #pragma unroll
        for (int kt = 0; kt < 16; ++kt) {
            short8v af = *(const short8v*)(Ap + kt * 32);
            short8v bf = *(const short8v*)&Bl[cn * LROW + kt * 32 + q * 8];
            acc = __builtin_amdgcn_mfma_f32_16x16x32_bf16(af, bf, acc, 0, 0, 0);
        }
    }
    if (NSEG == 2) {
        const ushort_t* Ap = a1 + (size_t)(wave * 16 + cn) * 512 + q * 8;
        #pragma unroll
        for (int kt = 0; kt < 16; ++kt) {
            short8v af = *(const short8v*)(Ap + kt * 32);
            short8v bf = *(const short8v*)&Bl[cn * LROW + 512 + kt * 32 + q * 8];
            acc = __builtin_amdgcn_mfma_f32_16x16x32_bf16(af, bf, acc, 0, 0, 0);
        }
    }
    #pragma unroll
    for (int rr = 0; rr < 4; ++rr)
        sbuf[(size_t)(wave * 16 + q * 4 + rr) * FIVEL + n0 + cn] = acc[rr];
}

// ---------------------------------------------------------------------------
// Step phase B (R8-proven): maxout-LSTM epilogue. 64 blocks. (final enc step)
// ---------------------------------------------------------------------------
__global__ __launch_bounds__(256)
void lstm_epi(const float* __restrict__ s, const ushort_t* __restrict__ pre,
              const float* __restrict__ b0, const float* __restrict__ b1,
              const float* __restrict__ c_in, float* __restrict__ c_out,
              ushort_t* __restrict__ h_out, ushort_t* __restrict__ h_copy)
{
    int idx = blockIdx.x * 256 + threadIdx.x;
    int row = idx >> 8;
    int c   = (idx & 255) * 2;
    float sg[5][2];
    #pragma unroll
    for (int g = 0; g < 5; ++g) {
        float2 v = *(const float2*)(s + (size_t)row * FIVEL + g * 512 + c);
        sg[g][0] = v.x + b0[g * 512 + c];
        sg[g][1] = v.y + b0[g * 512 + c + 1];
        if (b1) {
            sg[g][0] += b1[g * 512 + c];
            sg[g][1] += b1[g * 512 + c + 1];
        }
        if (pre) {
            ushort2 p = *(const ushort2*)(pre + (size_t)row * FIVEL + g * 512 + c);
            sg[g][0] += bf2f(p.x);
            sg[g][1] += bf2f(p.y);
        }
    }
    float2 ci = *(const float2*)(c_in + (size_t)row * 512 + c);
    float cc[2] = {ci.x, ci.y};
    ushort_t hh[2];
    #pragma unroll
    for (int e = 0; e < 2; ++e) {
        float ig = sigmoidf_(sg[0][e]), fg = sigmoidf_(sg[1][e]), og = sigmoidf_(sg[2][e]);
        float tt = fmaxf(sg[3][e], sg[4][e]);
        float c2 = fg * cc[e] + ig * tt;
        cc[e] = c2;
        hh[e] = f2bf(og * tanh_fast(c2));
    }
    *(float2*)(c_out + (size_t)row * 512 + c) = make_float2(cc[0], cc[1]);
    ushort2 ho = {hh[0], hh[1]};
    *(ushort2*)(h_out + (size_t)row * 512 + c) = ho;
    if (h_copy) *(ushort2*)(h_copy + (size_t)row * 512 + c) = ho;
}

// ---------------------------------------------------------------------------
// Fused epilogue + next-step attention (R10-proven). Block = batch b.
// ---------------------------------------------------------------------------
__global__ __launch_bounds__(256)
void epi_att(const float* __restrict__ s, const ushort_t* __restrict__ hprev,
             const ushort_t* __restrict__ pre,
             const float* __restrict__ b0, const float* __restrict__ b1,
             const ushort_t* __restrict__ tpw, const float* __restrict__ alpha_in,
             const float* __restrict__ c_in, float* __restrict__ c_out,
             ushort_t* __restrict__ h_out, ushort_t* __restrict__ h_copy,
             const ushort_t* __restrict__ projBase, long projLd,
             const ushort_t* __restrict__ feats,
             const ushort_t* __restrict__ W2aT, const float* __restrict__ b2a,
             const float* __restrict__ Watt,
             ushort_t* __restrict__ attv_out, float* __restrict__ alphas_out, int A)
{
    __shared__ ushort_t hl[512];
    __shared__ float hp[512];
    __shared__ float ealpha[128];
    const int b = blockIdx.x;
    const int tid = threadIdx.x, wave = tid >> 6, lane = tid & 63;

    if (s) {
        const int c = tid * 2;
        float al[8];
        if (tpw) {
            #pragma unroll
            for (int a = 0; a < 8; ++a) al[a] = alpha_in[b * 8 + a];
        }
        float sg[5][2];
        #pragma unroll
        for (int g = 0; g < 5; ++g) {
            float2 v = *(const float2*)(s + (size_t)b * FIVEL + g * 512 + c);
            sg[g][0] = v.x + b0[g * 512 + c];
            sg[g][1] = v.y + b0[g * 512 + c + 1];
            if (b1) {
                sg[g][0] += b1[g * 512 + c];
                sg[g][1] += b1[g * 512 + c + 1];
            }
            if (pre) {
                ushort2 p = *(const ushort2*)(pre + (size_t)b * FIVEL + g * 512 + c);
                sg[g][0] += bf2f(p.x);
                sg[g][1] += bf2f(p.y);
            }
            if (tpw) {
                #pragma unroll
                for (int a = 0; a < 8; ++a) {
                    ushort2 tv = *(const ushort2*)(tpw + ((size_t)a * 64 + b) * FIVEL + g * 512 + c);
                    sg[g][0] += al[a] * bf2f(tv.x);
                    sg[g][1] += al[a] * bf2f(tv.y);
                }
            }
        }
        float2 ci = *(const float2*)(c_in + (size_t)b * 512 + c);
        float cc[2] = {ci.x, ci.y};
        ushort_t hh[2];
        #pragma unroll
        for (int e = 0; e < 2; ++e) {
            float ig = sigmoidf_(sg[0][e]), fg = sigmoidf_(sg[1][e]), og = sigmoidf_(sg[2][e]);
            float tt = fmaxf(sg[3][e], sg[4][e]);
            float c2 = fg * cc[e] + ig * tt;
            cc[e] = c2;
            hh[e] = f2bf(og * tanh_fast(c2));
        }
        *(float2*)(c_out + (size_t)b * 512 + c) = make_float2(cc[0], cc[1]);
        ushort2 ho = {hh[0], hh[1]};
        *(ushort2*)(h_out + (size_t)b * 512 + c) = ho;
        if (h_copy) *(ushort2*)(h_copy + (size_t)b * 512 + c) = ho;
        *(ushort2*)&hl[c] = ho;
    } else {
        *(ushort2*)&hl[tid * 2] = *(const ushort2*)(hprev + (size_t)b * 512 + tid * 2);
    }
    if (!W2aT) return;
    __syncthreads();

    const int q = lane >> 4, cn = lane & 15;
    floatx4 acc[8] = {};
    {
        const ushort_t* Bp = W2aT + (size_t)(wave * 128 + cn) * 512 + q * 8;
        #pragma unroll 2
        for (int kt = 0; kt < 16; ++kt) {
            short8v af = *(const short8v*)&hl[kt * 32 + q * 8];
            #pragma unroll
            for (int t8 = 0; t8 < 8; ++t8) {
                short8v bf = *(const short8v*)(Bp + (size_t)t8 * 16 * 512 + kt * 32);
                acc[t8] = __builtin_amdgcn_mfma_f32_16x16x32_bf16(af, bf, acc[t8], 0, 0, 0);
            }
        }
    }
    if (q == 0) {
        #pragma unroll
        for (int t8 = 0; t8 < 8; ++t8) {
            int n = wave * 128 + t8 * 16 + cn;
            hp[n] = acc[t8][0] + b2a[n];
        }
    }
    __syncthreads();

    float hpr[8], war[8];
    {
        float4 w0 = *(const float4*)(Watt + lane * 8);
        float4 w1 = *(const float4*)(Watt + lane * 8 + 4);
        war[0] = w0.x; war[1] = w0.y; war[2] = w0.z; war[3] = w0.w;
        war[4] = w1.x; war[5] = w1.y; war[6] = w1.z; war[7] = w1.w;
        #pragma unroll
        for (int j = 0; j < 8; ++j) hpr[j] = hp[lane * 8 + j];
    }

    for (int a = wave; a < A; a += 4) {
        short8v pv = *(const short8v*)(projBase + ((size_t)a * 64 + b) * projLd + lane * 8);
        float e = 0.f;
        #pragma unroll
        for (int j = 0; j < 8; ++j)
            e += tanh_fast(bf2f((ushort_t)pv[j]) + hpr[j]) * war[j];
        #pragma unroll
        for (int off = 32; off; off >>= 1) e += __shfl_xor(e, off);
        if (lane == 0) ealpha[a] = e;
    }
    __syncthreads();
    if (wave == 0) {
        float v1 = (lane < A) ? ealpha[lane] : -3.0e38f;
        float v2 = (lane + 64 < A) ? ealpha[lane + 64] : -3.0e38f;
        float mm = fmaxf(v1, v2);
        #pragma unroll
        for (int off = 32; off; off >>= 1) mm = fmaxf(mm, __shfl_xor(mm, off));
        float x1 = (lane < A) ? __expf(v1 - mm) : 0.f;
        float x2 = (lane + 64 < A) ? __expf(v2 - mm) : 0.f;
        float ss = x1 + x2;
        #pragma unroll
        for (int off = 32; off; off >>= 1) ss += __shfl_xor(ss, off);
        float inv = 1.f / ss;
        if (lane < A) ealpha[lane] = x1 * inv;
        if (lane + 64 < A) ealpha[lane + 64] = x2 * inv;
    }
    __syncthreads();

    if (attv_out) {
        float s0 = 0.f, s1 = 0.f;
        for (int a = 0; a < A; ++a) {
            float alv = ealpha[a];
            unsigned int u = *(const unsigned int*)(feats + ((size_t)a * 64 + b) * 512 + tid * 2);
            s0 += alv * bf2f((ushort_t)(u & 0xffffu));
            s1 += alv * bf2f((ushort_t)(u >> 16));
        }
        ushort2 o = { f2bf(s0), f2bf(s1) };
        *(ushort2*)(attv_out + (size_t)b * 512 + tid * 2) = o;
    } else {
        if (tid < A) alphas_out[b * A + tid] = ealpha[tid];
    }
}

// ---------------------------------------------------------------------------
// Standalone attention (R8-proven) for the review r=0 bootstrap.
// ---------------------------------------------------------------------------
__global__ __launch_bounds__(256)
void attfuse2(const ushort_t* __restrict__ hprev,
              const ushort_t* __restrict__ projBase, long projLd,
              const ushort_t* __restrict__ feats,
              const ushort_t* __restrict__ W2aT, const float* __restrict__ b2a,
              const float* __restrict__ Watt, ushort_t* __restrict__ attv, int A)
{
    __shared__ float hp[512];
    __shared__ float ealpha[128];
    const int b = blockIdx.x;
    const int tid = threadIdx.x, wave = tid >> 6, lane = tid & 63;
    const int q = lane >> 4, cn = lane & 15;

    floatx4 acc[8] = {};
    {
        const ushort_t* Ap = hprev + (size_t)b * 512 + q * 8;
        const ushort_t* Bp = W2aT + (size_t)(wave * 128 + cn) * 512 + q * 8;
        #pragma unroll 2
        for (int kt = 0; kt < 16; ++kt) {
            short8v af = *(const short8v*)(Ap + kt * 32);
            #pragma unroll
            for (int t8 = 0; t8 < 8; ++t8) {
                short8v bf = *(const short8v*)(Bp + (size_t)t8 * 16 * 512 + kt * 32);
                acc[t8] = __builtin_amdgcn_mfma_f32_16x16x32_bf16(af, bf, acc[t8], 0, 0, 0);
            }
        }
    }
    if (q == 0) {
        #pragma unroll
        for (int t8 = 0; t8 < 8; ++t8) {
            int n = wave * 128 + t8 * 16 + cn;
            hp[n] = acc[t8][0] + b2a[n];
        }
    }
    __syncthreads();

    float hpr[8], war[8];
    {
        float4 w0 = *(const float4*)(Watt + lane * 8);
        float4 w1 = *(const float4*)(Watt + lane * 8 + 4);
        war[0] = w0.x; war[1] = w0.y; war[2] = w0.z; war[3] = w0.w;
        war[4] = w1.x; war[5] = w1.y; war[6] = w1.z; war[7] = w1.w;
        #pragma unroll
        for (int j = 0; j < 8; ++j) hpr[j] = hp[lane * 8 + j];
    }

    for (int a = wave; a < A; a += 4) {
        short8v pv = *(const short8v*)(projBase + ((size_t)a * 64 + b) * projLd + lane * 8);
        float e = 0.f;
        #pragma unroll
        for (int j = 0; j < 8; ++j)
            e += tanh_fast(bf2f((ushort_t)pv[j]) + hpr[j]) * war[j];
        #pragma unroll
        for (int off = 32; off; off >>= 1) e += __shfl_xor(e, off);
        if (lane == 0) ealpha[a] = e;
    }
    __syncthreads();
    if (wave == 0) {
        float v1 = (lane < A) ? ealpha[lane] : -3.0e38f;
        float v2 = (lane + 64 < A) ? ealpha[lane + 64] : -3.0e38f;
        float mm = fmaxf(v1, v2);
        #pragma unroll
        for (int off = 32; off; off >>= 1) mm = fmaxf(mm, __shfl_xor(mm, off));
        float x1 = (lane < A) ? __expf(v1 - mm) : 0.f;
        float x2 = (lane + 64 < A) ? __expf(v2 - mm) : 0.f;
        float ss = x1 + x2;
        #pragma unroll
        for (int off = 32; off; off >>= 1) ss += __shfl_xor(ss, off);
        float inv = 1.f / ss;
        if (lane < A) ealpha[lane] = x1 * inv;
        if (lane + 64 < A) ealpha[lane + 64] = x2 * inv;
    }
    __syncthreads();

    float s0 = 0.f, s1 = 0.f;
    for (int a = 0; a < A; ++a) {
        float al = ealpha[a];
        unsigned int u = *(const unsigned int*)(feats + ((size_t)a * 64 + b) * 512 + tid * 2);
        s0 += al * bf2f((ushort_t)(u & 0xffffu));
        s1 += al * bf2f((ushort_t)(u >> 16));
    }
    ushort2 o = { f2bf(s0), f2bf(s1) };
    *(ushort2*)(attv + (size_t)b * 512 + tid * 2) = o;
}

// ---------------------------------------------------------------------------
extern "C" void kernel_launch(void* const* d_in, const int* in_sizes, int n_in,
                              void* d_out_, int out_size, void* d_ws, size_t ws_size,
                              hipStream_t stream)
{
    const int*   code     = (const int*)  d_in[0];
    const int*   comment  = (const int*)  d_in[1];
    const float* embed    = (const float*)d_in[3];
    const float* enc_Wi   = (const float*)d_in[4];
    const float* enc_bi   = (const float*)d_in[5];
    const float* enc_Wh   = (const float*)d_in[6];
    const float* enc_bh   = (const float*)d_in[7];
    const float* rev_Wh   = (const float*)d_in[8];
    const float* rev_bh   = (const float*)d_in[9];
    const float* rev_Wa   = (const float*)d_in[10];
    const float* rev_ba   = (const float*)d_in[11];
    const float* rev_Wa2a = (const float*)d_in[12];
    const float* rev_ba2a = (const float*)d_in[13];
    const float* rev_Wh2a = (const float*)d_in[14];
    const float* rev_bh2a = (const float*)d_in[15];
    const float* rev_Watt = (const float*)d_in[16];
    const float* dec_Wi   = (const float*)d_in[18];
    const float* dec_bi   = (const float*)d_in[19];
    const float* dec_Wh   = (const float*)d_in[20];
    const float* dec_bh   = (const float*)d_in[21];
    const float* dec_Wa   = (const float*)d_in[22];
    const float* dec_ba   = (const float*)d_in[23];
    const float* dec_Wa2a = (const float*)d_in[24];
    const float* dec_ba2a = (const float*)d_in[25];
    const float* dec_Wh2a = (const float*)d_in[26];
    const float* dec_bh2a = (const float*)d_in[27];
    const float* dec_Watt = (const float*)d_in[28];
    const float* logit_W  = (const float*)d_in[30];
    const float* logit_b  = (const float*)d_in[31];
    float* out = (float*)d_out_;

    float* ws = (float*)d_ws;
    if (ws_size < WS_TOTAL * sizeof(float)) return;

    ushort_t* enc_pre_b = (ushort_t*)(ws + OFF_A);
    ushort_t* rev_projA = (ushort_t*)(ws + OFF_A);
    ushort_t* logit_WT  = (ushort_t*)(ws + OFF_LOGWT);
    ushort_t* dec_h_b   = (ushort_t*)(ws + OFF_DECH);
    ushort_t* dec_pre_b = (ushort_t*)(ws + OFF_DECPRE);
    ushort_t* WiT_enc   = (ushort_t*)(ws + OFF_WIT_ENC);
    ushort_t* enc_x_b   = (ushort_t*)(ws + OFF_ENCX);
    ushort_t* enc_hs_b  = (ushort_t*)(ws + OFF_ENC_HS);
    ushort_t* TPW       = (ushort_t*)(ws + OFF_TPW);
    ushort_t* encWhT    = (ushort_t*)(ws + OFF_ENC_WHT);
    ushort_t* revWcomb  = (ushort_t*)(ws + OFF_REVWC);
    float2*   part      = (float2*)(ws + OFF_PART);
    ushort_t* decWhT    = (ushort_t*)(ws + OFF_DECWC);
    ushort_t* WaT_dec   = (ushort_t*)(ws + OFF_DECWC + 655360);
    ushort_t* WiT_dec   = (ushort_t*)(ws + OFF_WIT_DEC);
    ushort_t* revWT     = (ushort_t*)(ws + OFF_REVWT);
    ushort_t* decWT     = (ushort_t*)(ws + OFF_DECWT);
    ushort_t* revWh2aT  = (ushort_t*)(ws + OFF_REVWH2AT);
    ushort_t* decWh2aT  = (ushort_t*)(ws + OFF_DECWH2AT);
    ushort_t* dec_x_b   = (ushort_t*)(ws + OFF_DECX);
    ushort_t* thought_b = (ushort_t*)(ws + OFF_THOUGHT);
    ushort_t* tproj_b   = (ushort_t*)(ws + OFF_TPROJ);
    ushort_t* hb[2] = { (ushort_t*)(ws + OFF_HB0), (ushort_t*)(ws + OFF_HB1) };
    ushort_t* attv_b    = (ushort_t*)(ws + OFF_ATTV);
    float*    sb[2]     = { ws + OFF_SBUF, ws + OFF_SBUF1 };
    float*    alphas    = ws + OFF_ALPHA;
    float* cbuf[4];
    for (int i = 0; i < 4; ++i) cbuf[i] = ws + OFF_C0 + (size_t)i * 32768;

    const dim3 blk(256);

    (void)hipMemsetAsync(cbuf[0], 0, (size_t)BB * LDIM * sizeof(float), stream);

    // ---- prep: gathers + batched weight transposes ----
    gather_embed<<<TENC * BB, 128, 0, stream>>>(embed, code, TENC, enc_x_b);
    gather_embed<<<TDEC * BB, 128, 0, stream>>>(embed, comment, TDEC, dec_x_b);
    conv_transpose5<<<dim3(80, 16, 5), blk, 0, stream>>>(
        enc_Wi, enc_Wh, dec_Wi, dec_Wh, dec_Wa,
        WiT_enc, encWhT, WiT_dec, decWhT, WaT_dec);
    conv_transpose_rev<<<dim3(80, 16, 16), blk, 0, stream>>>(rev_Wh, rev_Wa, revWcomb);
    conv_transpose_sq<<<dim3(16, 16, 16), blk, 0, stream>>>(
        rev_Wa2a, rev_Wh2a, revWT, revWh2aT, 8, 262144, 262144);
    conv_transpose_sq<<<dim3(16, 16, 2), blk, 0, stream>>>(
        dec_Wa2a, dec_Wh2a, decWT, decWh2aT, 1, 0, 0);

    // ---- hoisted encoder input GEMM: enc_pre = enc_x @ Wi + bi ----
    gemm_bf16<<<dim3(FIVEL / 128, TENC * BB / 128), blk, 0, stream>>>(
        enc_x_b, WiT_enc, enc_bi, enc_pre_b, FIVEL, EE, FIVEL);

    // ---- encoder scan: merged 1-kernel steps + final epilogue ----
    // M_t (t=1..99): h(t-1),c(t-1) = epi(s(t-1), pre(t-1), c(t-2));
    //                s(t) = h(t-1) @ Wh   -> sb[t&1]
    for (int t = 1; t < TENC; ++t) {
        enc_step_fused<<<80, blk, 0, stream>>>(
            (t == 1) ? nullptr : sb[(t - 1) & 1],
            enc_pre_b + (size_t)(t - 1) * 163840,
            enc_bh,
            (t == 1) ? cbuf[0] : cbuf[2 + ((t - 2) & 1)],
            cbuf[2 + ((t - 1) & 1)],
            enc_hs_b + (size_t)(t - 1) * 32768,
            encWhT,
            sb[t & 1]);
    }
    // final epilogue: h(99), c(99)=c_enc -> cbuf[0]
    lstm_epi<<<64, blk, 0, stream>>>(
        sb[(TENC - 1) & 1], enc_pre_b + (size_t)(TENC - 1) * 163840, enc_bh, nullptr,
        cbuf[2 + ((TENC - 2) & 1)], cbuf[0],
        enc_hs_b + (size_t)(TENC - 1) * 32768, nullptr);
    const ushort_t* h_enc = enc_hs_b + (size_t)(TENC - 1) * 32768;

    // ---- hoisted review projections: rev_projA[m][r*512+n] ----
    gemm_bf16<<<dim3(32, 50), blk, 0, stream>>>(
        enc_hs_b, revWT, rev_ba2a, rev_projA, 4096, LDIM, 4096);

    // ---- review scan: bootstrap attv(0), then {step_gemm, epi_att} ----
    attfuse2<<<BB, blk, 0, stream>>>(
        h_enc, rev_projA, 4096, enc_hs_b,
        revWh2aT, rev_bh2a, rev_Watt, attv_b, TENC);
    const ushort_t* rh = h_enc;
    for (int r = 0; r < RSTEPS; ++r) {
        step_gemm<2><<<160, blk, 0, stream>>>(
            rh, attv_b, revWcomb + (size_t)r * 2621440, 1024, sb[0]);
        const float* ci = (r == 0) ? cbuf[0] : cbuf[2 + ((r - 1) & 1)];
        const ushort_t* nextW = (r < RSTEPS - 1) ? revWh2aT + (size_t)(r + 1) * 262144 : nullptr;
        epi_att<<<BB, blk, 0, stream>>>(
            sb[0], nullptr, nullptr,
            rev_bh + (size_t)r * FIVEL, rev_ba + (size_t)r * FIVEL,
            nullptr, nullptr,
            ci, cbuf[2 + (r & 1)],
            hb[r & 1], thought_b + (size_t)r * 32768,
            rev_projA + (size_t)(r + 1) * 512, 4096, enc_hs_b,
            nextW, rev_bh2a + (size_t)(r + 1) * 512, rev_Watt + (size_t)(r + 1) * 512,
            attv_b, nullptr, TENC);
        rh = hb[r & 1];
    }

    // ---- tproj + logit_WT + dec_pre + TPW (rev regions now dead) ----
    gemm_bf16<<<dim3(4, 4), blk, 0, stream>>>(
        thought_b, decWT, dec_ba2a, tproj_b, HDIM, LDIM, HDIM);
    conv_transpose<<<dim3((VOUT + 31) / 32, 16, 1), blk, 0, stream>>>(
        logit_W, logit_WT, VOUT, 512, 0);
    gemm_bf16<<<dim3(FIVEL / 128, TDEC * BB / 128), blk, 0, stream>>>(
        dec_x_b, WiT_dec, dec_bi, dec_pre_b, FIVEL, EE, FIVEL);
    gemm_bf16<<<dim3(20, 4), blk, 0, stream>>>(
        thought_b, WaT_dec, nullptr, TPW, FIVEL, LDIM, FIVEL);

    // ---- decoder scan: bootstrap alpha(0), then {step_gemm<1>, epi_att} ----
    epi_att<<<BB, blk, 0, stream>>>(
        nullptr, h_enc, nullptr, nullptr, nullptr, nullptr, nullptr,
        nullptr, nullptr, nullptr, nullptr,
        tproj_b, 512, nullptr,
        decWh2aT, dec_bh2a, dec_Watt, nullptr, alphas, RSTEPS);
    for (int t = 0; t < TDEC; ++t) {
        const ushort_t* dh = (t == 0) ? h_enc : hb[(t - 1) & 1];
        step_gemm<1><<<160, blk, 0, stream>>>(dh, nullptr, decWhT, 512, sb[0]);
        const float* ci = (t == 0) ? cbuf[0] : cbuf[2 + ((t - 1) & 1)];
        const ushort_t* nextW = (t < TDEC - 1) ? decWh2aT : nullptr;
        epi_att<<<BB, blk, 0, stream>>>(
            sb[0], nullptr, dec_pre_b + (size_t)t * 163840,
            dec_bh, dec_ba,
            TPW, alphas,
            ci, cbuf[2 + (t & 1)],
            hb[t & 1], dec_h_b + (size_t)t * 32768,
            tproj_b, 512, nullptr,
            nextW, dec_bh2a, dec_Watt, nullptr, alphas, RSTEPS);
    }

    // ---- logit GEMM (XCD-swizzled, fused softmax partials) + lse pass ----
    gemm_logit<<<dim3(235 * 25), blk, 0, stream>>>(
        dec_h_b, logit_WT, logit_b, out, part, VOUT, LDIM);
    logsm_sub<<<TDEC * BB, blk, 0, stream>>>(out, part);
}